// Round 2
// baseline (389.899 us; speedup 1.0000x reference)
//
#include <hip/hip_runtime.h>
#include <math.h>

#define N_USERS 50000
#define N_ITEMS 100000
#define N_ENT   200000
#define N_NODES (N_USERERS_dummy)   // (unused guard)
#undef  N_NODES
#define N_NODES (N_USERS + N_ITEMS)
#define N_REL   32
#define DIM     64

#define NB_KG  391          // KG buckets: dst>>9 (512 keys each)
#define NB_UI  586          // UI buckets: row>>8 (256 keys each)
#define NB_TOT (NB_KG + NB_UI)   // 977
#define CAPD   4096         // max KEPT edges per bucket (post-filter; ~2.5K max expected)

__device__ __forceinline__ unsigned short f2bf(float f) {   // RNE f32->bf16
    unsigned u = __float_as_uint(f);
    u += 0x7FFFu + ((u >> 16) & 1u);
    return (unsigned short)(u >> 16);
}
__device__ __forceinline__ float bf_lo(unsigned v) { return __uint_as_float(v << 16); }
__device__ __forceinline__ float bf_hi(unsigned v) { return __uint_as_float(v & 0xFFFF0000u); }
__device__ __forceinline__ int getbit(const unsigned* m, int i) {
    return (m[i >> 5] >> (i & 31)) & 1;
}

// ---------------------------------------------------------------------------
// ent_matmul: y16 = bf16(x @ W^T), register-tiled LDS GEMM (R7 form).
// ---------------------------------------------------------------------------
__global__ __launch_bounds__(128) void ent_matmul(const float* __restrict__ x,
                                                  const float* __restrict__ w,
                                                  unsigned short* __restrict__ y16,
                                                  int n_ent) {
    __shared__ float xt[64][132];
    __shared__ float wt[64][68];
    int tid  = threadIdx.x;
    int base = blockIdx.x * 128;

    #pragma unroll
    for (int q = 0; q < 8; q++) {
        int idx = q * 128 + tid;
        int j = idx >> 4, k4 = idx & 15;
        float4 v = ((const float4*)w)[idx];
        wt[4 * k4 + 0][j] = v.x;
        wt[4 * k4 + 1][j] = v.y;
        wt[4 * k4 + 2][j] = v.z;
        wt[4 * k4 + 3][j] = v.w;
    }
    #pragma unroll
    for (int q = 0; q < 16; q++) {
        int idx = q * 128 + tid;
        int r = idx >> 4, k4 = idx & 15;
        int gr = base + r;
        if (gr < n_ent) {
            float4 v = ((const float4*)x)[(long)gr * 16 + k4];
            xt[4 * k4 + 0][r] = v.x;
            xt[4 * k4 + 1][r] = v.y;
            xt[4 * k4 + 2][r] = v.z;
            xt[4 * k4 + 3][r] = v.w;
        }
    }
    __syncthreads();

    int j0 = (tid & 7) * 8;
    int r0 = (tid >> 3) * 8;
    float acc[8][8];
    #pragma unroll
    for (int i = 0; i < 8; i++)
        #pragma unroll
        for (int j = 0; j < 8; j++) acc[i][j] = 0.f;

    #pragma unroll 4
    for (int k = 0; k < 64; k++) {
        float4 xa = *(const float4*)&xt[k][r0];
        float4 xb = *(const float4*)&xt[k][r0 + 4];
        float4 wa = *(const float4*)&wt[k][j0];
        float4 wb = *(const float4*)&wt[k][j0 + 4];
        float xr[8] = {xa.x, xa.y, xa.z, xa.w, xb.x, xb.y, xb.z, xb.w};
        float wr[8] = {wa.x, wa.y, wa.z, wa.w, wb.x, wb.y, wb.z, wb.w};
        #pragma unroll
        for (int i = 0; i < 8; i++)
            #pragma unroll
            for (int j = 0; j < 8; j++)
                acc[i][j] += xr[i] * wr[j];
    }

    #pragma unroll
    for (int i = 0; i < 8; i++) {
        int gr = base + r0 + i;
        if (gr < n_ent) {
            uint4 o;
            o.x = (unsigned)f2bf(acc[i][0]) | ((unsigned)f2bf(acc[i][1]) << 16);
            o.y = (unsigned)f2bf(acc[i][2]) | ((unsigned)f2bf(acc[i][3]) << 16);
            o.z = (unsigned)f2bf(acc[i][4]) | ((unsigned)f2bf(acc[i][5]) << 16);
            o.w = (unsigned)f2bf(acc[i][6]) | ((unsigned)f2bf(acc[i][7]) << 16);
            *(uint4*)&y16[(long)gr * 64 + j0] = o;
        }
    }
}

// ---------------------------------------------------------------------------
// build_masks: membership bitmaps. ent_mask = i2e image (entities kgagg walks),
// node_mask = sample rows (rows ui_aggregate walks). Edges whose key is not
// marked are dead work for the whole pipeline (~68% of all edges).
// ---------------------------------------------------------------------------
__global__ __launch_bounds__(256) void build_masks(const int* __restrict__ i2e,
                                                   const int* __restrict__ u,
                                                   const int* __restrict__ ipos,
                                                   const int* __restrict__ ineg,
                                                   unsigned* __restrict__ ent_mask,
                                                   unsigned* __restrict__ node_mask,
                                                   int B) {
    int t = blockIdx.x * 256 + threadIdx.x;
    int stride = gridDim.x * 256;
    for (int i = t; i < N_ITEMS; i += stride) {
        int e = i2e[i];
        atomicOr(&ent_mask[e >> 5], 1u << (e & 31));
    }
    for (int i = t; i < 3 * B; i += stride) {
        int r = (i < B) ? u[i]
              : (i < 2 * B) ? N_USERS + ipos[i - B]
                            : N_USERS + ineg[i - 2 * B];
        atomicOr(&node_mask[r >> 5], 1u << (r & 31));
    }
}

// ---------------------------------------------------------------------------
// Pass A: per-block LDS bucket histogram over KEPT edges only.
// Block 0 additionally precomputes the sigmoid gate table ONCE into gateg.
// ---------------------------------------------------------------------------
__global__ __launch_bounds__(256) void bucket_hist(const int* __restrict__ kg_dst,
                                                   const int* __restrict__ ui_row,
                                                   const unsigned* __restrict__ ent_mask,
                                                   const unsigned* __restrict__ node_mask,
                                                   const float* __restrict__ rel_emb,
                                                   float2* __restrict__ gateg,
                                                   int* __restrict__ bcnt,
                                                   int e_kg, int e_ui) {
    __shared__ int h[NB_TOT];
    for (int i = threadIdx.x; i < NB_TOT; i += 256) h[i] = 0;
    __syncthreads();
    if (blockIdx.x == 0) {
        for (int idx = threadIdx.x; idx < N_REL * 32; idx += 256) {
            int rel = idx >> 5, hl2 = idx & 31;
            float g0 = 1.0f / (1.0f + __expf(-rel_emb[rel * 64 + 2 * hl2]));
            float g1 = 1.0f / (1.0f + __expf(-rel_emb[rel * 64 + 2 * hl2 + 1]));
            gateg[idx] = make_float2(g0, g1);
        }
    }
    int n = e_kg + e_ui;
    int t = blockIdx.x * 256 + threadIdx.x;
    int stride = gridDim.x * 256;
    for (int e = t; e < n; e += stride) {
        int bk;
        if (e < e_kg) {
            int d = kg_dst[e];
            if (!getbit(ent_mask, d)) continue;
            bk = d >> 9;
        } else {
            int r = ui_row[e - e_kg];
            if (!getbit(node_mask, r)) continue;
            bk = NB_KG + (r >> 8);
        }
        atomicAdd(&h[bk], 1);
    }
    __syncthreads();
    for (int i = threadIdx.x; i < NB_TOT; i += 256)
        if (h[i]) atomicAdd(&bcnt[i], h[i]);
}

// ---------------------------------------------------------------------------
// Pass B: exclusive scan of bucket counts. boff[NB] = total KEPT edges
// (inclusive sum), since totals no longer equal e_kg/e_ui.
// ---------------------------------------------------------------------------
__global__ __launch_bounds__(256) void bucket_scan(const int* __restrict__ bcnt,
                                                   int* __restrict__ boff_kg,
                                                   int* __restrict__ boff_ui,
                                                   int* __restrict__ bcur) {
    __shared__ int sh[1024];
    int t = threadIdx.x;
    for (int seg = 0; seg < 2; seg++) {
        int NB = seg ? NB_UI : NB_KG;
        const int* src = bcnt + (seg ? NB_KG : 0);
        int idx[4] = { t, t + 256, t + 512, t + 768 };
        int v[4];
        #pragma unroll
        for (int q = 0; q < 4; q++) {
            v[q] = (idx[q] < NB) ? src[idx[q]] : 0;
            sh[idx[q]] = v[q];
        }
        __syncthreads();
        for (int o = 1; o < 1024; o <<= 1) {
            int a[4];
            #pragma unroll
            for (int q = 0; q < 4; q++) a[q] = (idx[q] >= o) ? sh[idx[q] - o] : 0;
            __syncthreads();
            #pragma unroll
            for (int q = 0; q < 4; q++) sh[idx[q]] += a[q];
            __syncthreads();
        }
        int* boff = seg ? boff_ui : boff_kg;
        int  base = seg ? NB_KG : 0;
        #pragma unroll
        for (int q = 0; q < 4; q++) {
            if (idx[q] < NB) {
                int ex = sh[idx[q]] - v[q];
                boff[idx[q]] = ex;
                bcur[base + idx[q]] = ex;
                if (idx[q] == NB - 1) boff[NB] = sh[idx[q]];
            }
        }
        __syncthreads();
    }
}

// ---------------------------------------------------------------------------
// Pass C: scatter KEPT edges into bucket regions.
// KG rec: src(18) | rel<<18 (5) | dst_local<<23 (9)
// UI rec: col(18) | row_local<<18 (8); parallel uval[] carries ui_vals[e].
// ---------------------------------------------------------------------------
__global__ __launch_bounds__(256) void bucket_scatter(const int* __restrict__ kg_src,
                                                      const int* __restrict__ kg_dst,
                                                      const int* __restrict__ kg_rel,
                                                      const int* __restrict__ ui_row,
                                                      const int* __restrict__ ui_col,
                                                      const float* __restrict__ ui_vals,
                                                      const unsigned* __restrict__ ent_mask,
                                                      const unsigned* __restrict__ node_mask,
                                                      int* __restrict__ bcur,
                                                      unsigned int* __restrict__ kgrec,
                                                      int* __restrict__ uirec,
                                                      float* __restrict__ uval,
                                                      int e_kg, int e_ui) {
    __shared__ int h[NB_TOT];
    __shared__ int lbase[NB_TOT];
    int n = e_kg + e_ui;
    int nchunks = (n + 4095) >> 12;
    int tid = threadIdx.x;
    for (int c = blockIdx.x; c < nchunks; c += gridDim.x) {
        int base = c << 12;
        for (int i = tid; i < NB_TOT; i += 256) h[i] = 0;
        __syncthreads();
        unsigned int rec[16];
        float val[16];
        int bk[16];
        #pragma unroll
        for (int j = 0; j < 16; j++) {
            int e = base + j * 256 + tid;
            bk[j] = -1;
            if (e < n) {
                if (e < e_kg) {
                    int d = kg_dst[e];
                    if (getbit(ent_mask, d)) {
                        bk[j]  = d >> 9;
                        rec[j] = (unsigned int)kg_src[e] | ((unsigned int)kg_rel[e] << 18)
                                 | ((unsigned int)(d & 511) << 23);
                        atomicAdd(&h[bk[j]], 1);
                    }
                } else {
                    int i2 = e - e_kg;
                    int r  = ui_row[i2];
                    if (getbit(node_mask, r)) {
                        bk[j]  = NB_KG + (r >> 8);
                        rec[j] = (unsigned int)ui_col[i2] | ((unsigned int)(r & 255) << 18);
                        val[j] = ui_vals[i2];
                        atomicAdd(&h[bk[j]], 1);
                    }
                }
            }
        }
        __syncthreads();
        for (int i = tid; i < NB_TOT; i += 256) {
            int cc = h[i];
            lbase[i] = cc ? atomicAdd(&bcur[i], cc) : 0;
        }
        __syncthreads();
        #pragma unroll
        for (int j = 0; j < 16; j++) {
            if (bk[j] >= 0) {
                int pos = atomicAdd(&lbase[bk[j]], 1);
                if (bk[j] < NB_KG) kgrec[pos] = rec[j];
                else               { uirec[pos] = (int)rec[j]; uval[pos] = val[j]; }
            }
        }
        __syncthreads();
    }
}

// ---------------------------------------------------------------------------
// Pass D: one block per bucket. LDS counting-sort of KEPT records; emits CSR
// off[] and sorted records (+reordered uval for UI). No dinv (ui_vals input
// replaces it). off totals come from boff[NB] (kept-edge totals).
// ---------------------------------------------------------------------------
__global__ __launch_bounds__(256) void bucket_finalize(const int* __restrict__ boff_kg,
                                                       const int* __restrict__ boff_ui,
                                                       unsigned int* __restrict__ kgrec,
                                                       int* __restrict__ uirec,
                                                       float* __restrict__ uval,
                                                       int* __restrict__ off_kg,
                                                       int* __restrict__ off_ui) {
    __shared__ unsigned int rec[CAPD];
    __shared__ float fval[CAPD];
    __shared__ int hist[512];
    bool iskg = blockIdx.x < NB_KG;
    int  b    = iskg ? blockIdx.x : blockIdx.x - NB_KG;
    const int* boff = iskg ? boff_kg : boff_ui;
    int ebeg = boff[b], eend = boff[b + 1];
    int ne   = min(eend - ebeg, CAPD);
    int key_base = iskg ? (b << 9) : (b << 8);
    int nkeys = iskg ? min(512, N_ENT - key_base) : min(256, N_NODES - key_base);
    int SH = iskg ? 23 : 18;
    int tid = threadIdx.x;

    for (int i = tid; i < ne; i += 256) {
        if (iskg) rec[i] = kgrec[ebeg + i];
        else { rec[i] = (unsigned int)uirec[ebeg + i]; fval[i] = uval[ebeg + i]; }
    }
    for (int i = tid; i < 512; i += 256) hist[i] = 0;
    __syncthreads();
    for (int i = tid; i < ne; i += 256)
        atomicAdd(&hist[rec[i] >> SH], 1);
    __syncthreads();
    int i0 = tid, i1 = tid + 256;
    int v0 = hist[i0], v1 = hist[i1];
    __syncthreads();
    for (int o = 1; o < 512; o <<= 1) {
        int a0 = (i0 >= o) ? hist[i0 - o] : 0;
        int a1 = (i1 >= o) ? hist[i1 - o] : 0;
        __syncthreads();
        hist[i0] += a0; hist[i1] += a1;
        __syncthreads();
    }
    int e0 = hist[i0] - v0, e1 = hist[i1] - v1;
    __syncthreads();
    hist[i0] = e0; hist[i1] = e1;
    int* offg = iskg ? off_kg : off_ui;
    if (i0 < nkeys) offg[key_base + i0] = ebeg + e0;
    if (i1 < nkeys) offg[key_base + i1] = ebeg + e1;
    if (blockIdx.x == 0 && tid == 0) {
        off_kg[N_ENT]   = boff_kg[NB_KG];
        off_ui[N_NODES] = boff_ui[NB_UI];
    }
    __syncthreads();
    for (int i = tid; i < ne; i += 256) {
        unsigned int r = rec[i];
        int k = r >> SH;
        int slot = atomicAdd(&hist[k], 1);
        if (iskg) kgrec[ebeg + slot] = r & 0x7FFFFFu;
        else      { uirec[ebeg + slot] = (int)(r & 0x3FFFFu); uval[ebeg + slot] = fval[i]; }
    }
}

// ---------------------------------------------------------------------------
// kgagg_build: ONE WAVE PER NODE. Users: write bf16 copy only (f32 all_emb
// user rows are never read — ui_aggregate reads user_emb directly). Items:
// KG aggregate on ent=i2e[it]; kept entities retain ALL their edges, so
// deg = end-beg is the full degree.
// ---------------------------------------------------------------------------
__global__ __launch_bounds__(256) void kgagg_build(const int* __restrict__ off,
                                                   const unsigned int* __restrict__ packed,
                                                   const unsigned short* __restrict__ y16,
                                                   const float* __restrict__ entity_emb,
                                                   const float* __restrict__ user_emb,
                                                   const int* __restrict__ i2e,
                                                   const float2* __restrict__ gateg,
                                                   float* __restrict__ all_emb,
                                                   unsigned short* __restrict__ all16) {
    int lane = threadIdx.x & 63;
    int w = (blockIdx.x * 256 + threadIdx.x) >> 6;
    if (w >= N_NODES) return;
    int hl   = lane & 31;
    int half = lane >> 5;

    if (w < N_USERS) {                    // user row: bf16 copy only
        if (half == 0) {
            float2 v = ((const float2*)user_emb)[(long)w * 32 + hl];
            ((unsigned*)all16)[(long)w * 32 + hl] =
                (unsigned)f2bf(v.x) | ((unsigned)f2bf(v.y) << 16);
        }
        return;
    }

    int ent = i2e[w - N_USERS];
    const unsigned* y32 = (const unsigned*)y16;
    int beg = off[ent], end = off[ent + 1];
    float ax0 = 0.f, ay0 = 0.f, ax1 = 0.f, ay1 = 0.f;
    float ax2 = 0.f, ay2 = 0.f, ax3 = 0.f, ay3 = 0.f;
    int p = beg;
    for (; p + 8 <= end; p += 8) {
        unsigned pk0 = packed[p + 0 + half];
        unsigned pk1 = packed[p + 2 + half];
        unsigned pk2 = packed[p + 4 + half];
        unsigned pk3 = packed[p + 6 + half];
        unsigned v0 = y32[(long)(pk0 & 0x3FFFF) * 32 + hl];
        unsigned v1 = y32[(long)(pk1 & 0x3FFFF) * 32 + hl];
        unsigned v2 = y32[(long)(pk2 & 0x3FFFF) * 32 + hl];
        unsigned v3 = y32[(long)(pk3 & 0x3FFFF) * 32 + hl];
        float2 g0 = gateg[(pk0 >> 18) * 32 + hl];
        float2 g1 = gateg[(pk1 >> 18) * 32 + hl];
        float2 g2 = gateg[(pk2 >> 18) * 32 + hl];
        float2 g3 = gateg[(pk3 >> 18) * 32 + hl];
        ax0 += bf_lo(v0) * g0.x;  ay0 += bf_hi(v0) * g0.y;
        ax1 += bf_lo(v1) * g1.x;  ay1 += bf_hi(v1) * g1.y;
        ax2 += bf_lo(v2) * g2.x;  ay2 += bf_hi(v2) * g2.y;
        ax3 += bf_lo(v3) * g3.x;  ay3 += bf_hi(v3) * g3.y;
    }
    for (; p + 2 <= end; p += 2) {
        unsigned pk = packed[p + half];
        unsigned v  = y32[(long)(pk & 0x3FFFF) * 32 + hl];
        float2 g = gateg[(pk >> 18) * 32 + hl];
        ax0 += bf_lo(v) * g.x;
        ay0 += bf_hi(v) * g.y;
    }
    if (p < end && half == 0) {
        unsigned pk = packed[p];
        unsigned v  = y32[(long)(pk & 0x3FFFF) * 32 + hl];
        float2 g = gateg[(pk >> 18) * 32 + hl];
        ax0 += bf_lo(v) * g.x;
        ay0 += bf_hi(v) * g.y;
    }
    float ax = (ax0 + ax1) + (ax2 + ax3);
    float ay = (ay0 + ay1) + (ay2 + ay3);
    ax += __shfl_xor(ax, 32);
    ay += __shfl_xor(ay, 32);
    float deg = fmaxf((float)(end - beg), 1.0f);
    float2 xv = ((const float2*)entity_emb)[(long)ent * 32 + hl];
    float v0 = ax / deg + xv.x;
    float v1 = ay / deg + xv.y;
    v0 = (v0 > 0.0f) ? v0 : (__expf(v0) - 1.0f);
    v1 = (v1 > 0.0f) ? v1 : (__expf(v1) - 1.0f);
    float ss = v0 * v0 + v1 * v1;
    #pragma unroll
    for (int o = 16; o; o >>= 1) ss += __shfl_xor(ss, o);
    float inv = 1.0f / fmaxf(sqrtf(ss), 1e-12f);
    if (half == 0) {
        float a = v0 * inv, b = v1 * inv;
        ((float2*)all_emb)[(long)w * 32 + hl] = make_float2(a, b);
        ((unsigned*)all16)[(long)w * 32 + hl] =
            (unsigned)f2bf(a) | ((unsigned)f2bf(b) << 16);
    }
}

// ---------------------------------------------------------------------------
// ui_aggregate_s: one wave per SAMPLE ROW (3B waves). Per-edge weight comes
// from the sorted uval[] (sequential load) — exactly the reference's
// ui_vals[e] multiplier. User-row residual read from user_emb directly.
// ---------------------------------------------------------------------------
__global__ __launch_bounds__(256) void ui_aggregate_s(const int* __restrict__ off,
                                                      const int* __restrict__ colrec,
                                                      const float* __restrict__ uval,
                                                      const float* __restrict__ all_emb,
                                                      const float* __restrict__ user_emb,
                                                      const unsigned short* __restrict__ all16,
                                                      const int* __restrict__ u,
                                                      const int* __restrict__ ipos,
                                                      const int* __restrict__ ineg,
                                                      float* __restrict__ final_emb, int B) {
    const unsigned* a32 = (const unsigned*)all16;
    int lane = threadIdx.x & 63;
    int hl   = lane & 31;
    int half = lane >> 5;
    int w = (blockIdx.x * 256 + threadIdx.x) >> 6;
    if (w >= 3 * B) return;
    int r;
    if (w < B)          r = u[w];
    else if (w < 2 * B) r = N_USERS + ipos[w - B];
    else                r = N_USERS + ineg[w - 2 * B];

    int beg = off[r], end = off[r + 1];
    float ax0 = 0.f, ay0 = 0.f, ax1 = 0.f, ay1 = 0.f;
    float ax2 = 0.f, ay2 = 0.f, ax3 = 0.f, ay3 = 0.f;
    int p = beg;
    for (; p + 8 <= end; p += 8) {
        int c0 = colrec[p + 0 + half];
        int c1 = colrec[p + 2 + half];
        int c2 = colrec[p + 4 + half];
        int c3 = colrec[p + 6 + half];
        float d0 = uval[p + 0 + half];
        float d1 = uval[p + 2 + half];
        float d2 = uval[p + 4 + half];
        float d3 = uval[p + 6 + half];
        unsigned v0 = a32[(long)c0 * 32 + hl];
        unsigned v1 = a32[(long)c1 * 32 + hl];
        unsigned v2 = a32[(long)c2 * 32 + hl];
        unsigned v3 = a32[(long)c3 * 32 + hl];
        ax0 += d0 * bf_lo(v0);  ay0 += d0 * bf_hi(v0);
        ax1 += d1 * bf_lo(v1);  ay1 += d1 * bf_hi(v1);
        ax2 += d2 * bf_lo(v2);  ay2 += d2 * bf_hi(v2);
        ax3 += d3 * bf_lo(v3);  ay3 += d3 * bf_hi(v3);
    }
    for (; p + 2 <= end; p += 2) {
        int c = colrec[p + half];
        float d = uval[p + half];
        unsigned v = a32[(long)c * 32 + hl];
        ax0 += d * bf_lo(v);
        ay0 += d * bf_hi(v);
    }
    if (p < end && half == 0) {
        int c = colrec[p];
        float d = uval[p];
        unsigned v = a32[(long)c * 32 + hl];
        ax0 += d * bf_lo(v);
        ay0 += d * bf_hi(v);
    }
    float ax = (ax0 + ax1) + (ax2 + ax3);
    float ay = (ay0 + ay1) + (ay2 + ay3);
    ax += __shfl_xor(ax, 32);
    ay += __shfl_xor(ay, 32);
    if (half == 0) {
        float2 ae = (r < N_USERS)
            ? ((const float2*)user_emb)[(long)r * 32 + hl]
            : ((const float2*)all_emb)[(long)r * 32 + hl];
        ((float2*)final_emb)[(long)r * 32 + hl] =
            make_float2(0.5f * (ae.x + ax), 0.5f * (ae.y + ay));
    }
}

// ---------------------------------------------------------------------------
// Epilogue (intent folded in): one wave per sample.
// ---------------------------------------------------------------------------
__global__ void final_kernel(const int* __restrict__ u, const int* __restrict__ ipos,
                             const int* __restrict__ ineg,
                             const float* __restrict__ final_emb,
                             const float* __restrict__ all_emb,
                             const float* __restrict__ rw, const float* __restrict__ rb,
                             const float* __restrict__ iw, const float* __restrict__ rel_emb,
                             float* __restrict__ out, int B) {
    __shared__ float sh_intent[128];
    if (threadIdx.x < 64) {
        int j = threadIdx.x;
        for (int k = 0; k < 2; k++) {
            float m = -1e30f;
            for (int r = 0; r < N_REL; r++) m = fmaxf(m, iw[k * N_REL + r]);
            float Z = 0.f, acc = 0.f;
            for (int r = 0; r < N_REL; r++) {
                float e = __expf(iw[k * N_REL + r] - m);
                Z += e;
                acc += e * rel_emb[r * 64 + j];
            }
            sh_intent[k * 64 + j] = acc / Z;
        }
    }
    __syncthreads();
    int lane = threadIdx.x & 63;
    int wave = (blockIdx.x * blockDim.x + threadIdx.x) >> 6;
    int nw   = (gridDim.x * blockDim.x) >> 6;
    for (int b = wave; b < B; b += nw) {
        int uu = u[b];
        float up = final_emb[(long)uu * 64 + lane];
        float l0 = up * rw[lane];
        float l1 = up * rw[64 + lane];
        #pragma unroll
        for (int o = 32; o; o >>= 1) {
            l0 += __shfl_xor(l0, o);
            l1 += __shfl_xor(l1, o);
        }
        l0 += rb[0]; l1 += rb[1];
        float m  = fmaxf(l0, l1);
        float e0 = __expf(l0 - m), e1 = __expf(l1 - m);
        float inv = 1.0f / (e0 + e1);
        float p0 = e0 * inv, p1 = e1 * inv;
        float ue = up + p0 * sh_intent[lane] + p1 * sh_intent[64 + lane];

        int it = ipos[b];
        long rr = (long)(N_USERS + it) * 64 + lane;
        float ie = final_emb[rr] + all_emb[rr];
        float dp = ue * ie;
        #pragma unroll
        for (int o = 32; o; o >>= 1) dp += __shfl_xor(dp, o);
        if (lane == 0) out[b] = dp;

        it = ineg[b];
        rr = (long)(N_USERS + it) * 64 + lane;
        ie = final_emb[rr] + all_emb[rr];
        dp = ue * ie;
        #pragma unroll
        for (int o = 32; o; o >>= 1) dp += __shfl_xor(dp, o);
        if (lane == 0) out[B + b] = dp;
    }
}

extern "C" void kernel_launch(void* const* d_in, const int* in_sizes, int n_in,
                              void* d_out, int out_size, void* d_ws, size_t ws_size,
                              hipStream_t stream) {
    const int*   u          = (const int*)  d_in[0];
    const int*   ipos       = (const int*)  d_in[1];
    const int*   ineg       = (const int*)  d_in[2];
    const float* user_emb   = (const float*)d_in[3];
    const float* entity_emb = (const float*)d_in[4];
    const float* rel_emb    = (const float*)d_in[5];
    const float* iw         = (const float*)d_in[6];
    const float* rw         = (const float*)d_in[7];
    const float* rb         = (const float*)d_in[8];
    const float* kgw        = (const float*)d_in[9];
    const float* ui_vals    = (const float*)d_in[10];
    const int*   i2e        = (const int*)  d_in[11];
    const int*   kg_src     = (const int*)  d_in[12];
    const int*   kg_dst     = (const int*)  d_in[13];
    const int*   kg_rel     = (const int*)  d_in[14];
    const int*   ui_row     = (const int*)  d_in[15];
    const int*   ui_col     = (const int*)  d_in[16];
    float*       out        = (float*)d_out;

    int B    = in_sizes[0];
    int e_kg = in_sizes[12];
    int e_ui = in_sizes[15];

    // ---------------- workspace layout (bytes) ----------------
    // Same total footprint as R1: old uirec(8MB) split into uirec(4MB)+uval(4MB)
    // (kept UI edges ~160K << 1M cap); masks reuse the old dinv region.
    char* ws = (char*)d_ws;
    unsigned short* y16       = (unsigned short*)(ws + 0);        // 25.6 MB
    float*          all_emb   = (float*)(ws + 25600000);          // 38.4 MB
    unsigned short* all16     = (unsigned short*)(ws + 64000000); // 19.2 MB
    float*          final_emb = (float*)(ws + 83200000);          // 38.4 MB (sparse use)
    unsigned int*   kgrec     = (unsigned int*)(ws + 121600000);  // 8 MB (kept KG <= 2M hard)
    int*            uirec     = (int*)(ws + 129600000);           // 4 MB (kept UI ~160K)
    float*          uval      = (float*)(ws + 133600000);         // 4 MB
    int*            off_kg    = (int*)(ws + 137600000);           // 200001 ints
    int*            off_ui    = (int*)(ws + 138400256);           // 150001 ints
    unsigned*       ent_mask  = (unsigned*)(ws + 139000512);      // 25088 B (200K bits)
    unsigned*       node_mask = (unsigned*)(ws + 139025600);      // 18752 B (150K bits)
    int*            bcnt      = (int*)(ws + 139600512);           // 977 ints
    int*            boff_kg   = (int*)(ws + 139604480);           // 392 ints
    int*            boff_ui   = (int*)(ws + 139606272);           // 587 ints
    int*            bcur      = (int*)(ws + 139608704);           // 977 ints
    float2*         gateg     = (float2*)(ws + 139612672);        // 8 KB gate table

    hipMemsetAsync(bcnt, 0, NB_TOT * sizeof(int), stream);
    hipMemsetAsync(ent_mask, 0, 25088 + 18752, stream);   // ent_mask + node_mask contiguous
    build_masks    <<<512, 256, 0, stream>>>(i2e, u, ipos, ineg, ent_mask, node_mask, B);
    bucket_hist    <<<1024, 256, 0, stream>>>(kg_dst, ui_row, ent_mask, node_mask,
                                              rel_emb, gateg, bcnt, e_kg, e_ui);
    bucket_scan    <<<1,   256, 0, stream>>>(bcnt, boff_kg, boff_ui, bcur);
    bucket_scatter <<<512, 256, 0, stream>>>(kg_src, kg_dst, kg_rel, ui_row, ui_col,
                                             ui_vals, ent_mask, node_mask,
                                             bcur, kgrec, uirec, uval, e_kg, e_ui);
    bucket_finalize<<<NB_TOT, 256, 0, stream>>>(boff_kg, boff_ui, kgrec, uirec, uval,
                                                off_kg, off_ui);

    ent_matmul <<<(N_ENT + 127) / 128, 128, 0, stream>>>(entity_emb, kgw, y16, N_ENT);
    kgagg_build<<<(N_NODES * 64 + 255) / 256, 256, 0, stream>>>(
        off_kg, kgrec, y16, entity_emb, user_emb, i2e, gateg, all_emb, all16);
    ui_aggregate_s<<<(3 * B * 64 + 255) / 256, 256, 0, stream>>>(
        off_ui, uirec, uval, all_emb, user_emb, all16, u, ipos, ineg, final_emb, B);
    final_kernel<<<256, 256, 0, stream>>>(u, ipos, ineg, final_emb, all_emb,
                                          rw, rb, iw, rel_emb, out, B);
}

// Round 3
// 373.754 us; speedup vs baseline: 1.0432x; 1.0432x over previous
//
#include <hip/hip_runtime.h>
#include <math.h>

#define N_USERS 50000
#define N_ITEMS 100000
#define N_ENT   200000
#define N_NODES (N_USERS + N_ITEMS)
#define N_REL   32
#define DIM     64

#define NB_KG  391          // KG buckets: dst>>9 (512 keys each)
#define NB_UI  586          // UI buckets: row>>8 (256 keys each)
#define NB_TOT (NB_KG + NB_UI)   // 977
#define CAPD   4096         // max KEPT edges per bucket (post-filter)

__device__ __forceinline__ unsigned short f2bf(float f) {   // RNE f32->bf16
    unsigned u = __float_as_uint(f);
    u += 0x7FFFu + ((u >> 16) & 1u);
    return (unsigned short)(u >> 16);
}
__device__ __forceinline__ float bf_lo(unsigned v) { return __uint_as_float(v << 16); }
__device__ __forceinline__ float bf_hi(unsigned v) { return __uint_as_float(v & 0xFFFF0000u); }
__device__ __forceinline__ int getbit(const unsigned* m, int i) {
    return (m[i >> 5] >> (i & 31)) & 1;
}

// ---------------------------------------------------------------------------
// ent_matmul: y16 = bf16(x @ W^T), register-tiled LDS GEMM (R7 form).
// ---------------------------------------------------------------------------
__global__ __launch_bounds__(128) void ent_matmul(const float* __restrict__ x,
                                                  const float* __restrict__ w,
                                                  unsigned short* __restrict__ y16,
                                                  int n_ent) {
    __shared__ float xt[64][132];
    __shared__ float wt[64][68];
    int tid  = threadIdx.x;
    int base = blockIdx.x * 128;

    #pragma unroll
    for (int q = 0; q < 8; q++) {
        int idx = q * 128 + tid;
        int j = idx >> 4, k4 = idx & 15;
        float4 v = ((const float4*)w)[idx];
        wt[4 * k4 + 0][j] = v.x;
        wt[4 * k4 + 1][j] = v.y;
        wt[4 * k4 + 2][j] = v.z;
        wt[4 * k4 + 3][j] = v.w;
    }
    #pragma unroll
    for (int q = 0; q < 16; q++) {
        int idx = q * 128 + tid;
        int r = idx >> 4, k4 = idx & 15;
        int gr = base + r;
        if (gr < n_ent) {
            float4 v = ((const float4*)x)[(long)gr * 16 + k4];
            xt[4 * k4 + 0][r] = v.x;
            xt[4 * k4 + 1][r] = v.y;
            xt[4 * k4 + 2][r] = v.z;
            xt[4 * k4 + 3][r] = v.w;
        }
    }
    __syncthreads();

    int j0 = (tid & 7) * 8;
    int r0 = (tid >> 3) * 8;
    float acc[8][8];
    #pragma unroll
    for (int i = 0; i < 8; i++)
        #pragma unroll
        for (int j = 0; j < 8; j++) acc[i][j] = 0.f;

    #pragma unroll 4
    for (int k = 0; k < 64; k++) {
        float4 xa = *(const float4*)&xt[k][r0];
        float4 xb = *(const float4*)&xt[k][r0 + 4];
        float4 wa = *(const float4*)&wt[k][j0];
        float4 wb = *(const float4*)&wt[k][j0 + 4];
        float xr[8] = {xa.x, xa.y, xa.z, xa.w, xb.x, xb.y, xb.z, xb.w};
        float wr[8] = {wa.x, wa.y, wa.z, wa.w, wb.x, wb.y, wb.z, wb.w};
        #pragma unroll
        for (int i = 0; i < 8; i++)
            #pragma unroll
            for (int j = 0; j < 8; j++)
                acc[i][j] += xr[i] * wr[j];
    }

    #pragma unroll
    for (int i = 0; i < 8; i++) {
        int gr = base + r0 + i;
        if (gr < n_ent) {
            uint4 o;
            o.x = (unsigned)f2bf(acc[i][0]) | ((unsigned)f2bf(acc[i][1]) << 16);
            o.y = (unsigned)f2bf(acc[i][2]) | ((unsigned)f2bf(acc[i][3]) << 16);
            o.z = (unsigned)f2bf(acc[i][4]) | ((unsigned)f2bf(acc[i][5]) << 16);
            o.w = (unsigned)f2bf(acc[i][6]) | ((unsigned)f2bf(acc[i][7]) << 16);
            *(uint4*)&y16[(long)gr * 64 + j0] = o;
        }
    }
}

// ---------------------------------------------------------------------------
// build_masks: membership bitmaps + zero bcnt (replaces one memset node;
// all blocks write 0 to bcnt — benign same-value race, done before hist).
// ---------------------------------------------------------------------------
__global__ __launch_bounds__(256) void build_masks(const int* __restrict__ i2e,
                                                   const int* __restrict__ u,
                                                   const int* __restrict__ ipos,
                                                   const int* __restrict__ ineg,
                                                   unsigned* __restrict__ ent_mask,
                                                   unsigned* __restrict__ node_mask,
                                                   int* __restrict__ bcnt,
                                                   int B) {
    int t = blockIdx.x * 256 + threadIdx.x;
    int stride = gridDim.x * 256;
    for (int i = threadIdx.x; i < NB_TOT; i += 256) bcnt[i] = 0;
    for (int i = t; i < N_ITEMS; i += stride) {
        int e = i2e[i];
        atomicOr(&ent_mask[e >> 5], 1u << (e & 31));
    }
    for (int i = t; i < 3 * B; i += stride) {
        int r = (i < B) ? u[i]
              : (i < 2 * B) ? N_USERS + ipos[i - B]
                            : N_USERS + ineg[i - 2 * B];
        atomicOr(&node_mask[r >> 5], 1u << (r & 31));
    }
}

// ---------------------------------------------------------------------------
// Pass A: per-block LDS bucket histogram over KEPT edges only.
// Block 0 additionally precomputes the sigmoid gate table ONCE into gateg.
// ---------------------------------------------------------------------------
__global__ __launch_bounds__(256) void bucket_hist(const int* __restrict__ kg_dst,
                                                   const int* __restrict__ ui_row,
                                                   const unsigned* __restrict__ ent_mask,
                                                   const unsigned* __restrict__ node_mask,
                                                   const float* __restrict__ rel_emb,
                                                   float2* __restrict__ gateg,
                                                   int* __restrict__ bcnt,
                                                   int e_kg, int e_ui) {
    __shared__ int h[NB_TOT];
    for (int i = threadIdx.x; i < NB_TOT; i += 256) h[i] = 0;
    __syncthreads();
    if (blockIdx.x == 0) {
        for (int idx = threadIdx.x; idx < N_REL * 32; idx += 256) {
            int rel = idx >> 5, hl2 = idx & 31;
            float g0 = 1.0f / (1.0f + __expf(-rel_emb[rel * 64 + 2 * hl2]));
            float g1 = 1.0f / (1.0f + __expf(-rel_emb[rel * 64 + 2 * hl2 + 1]));
            gateg[idx] = make_float2(g0, g1);
        }
    }
    int n = e_kg + e_ui;
    int t = blockIdx.x * 256 + threadIdx.x;
    int stride = gridDim.x * 256;
    for (int e = t; e < n; e += stride) {
        int bk;
        if (e < e_kg) {
            int d = kg_dst[e];
            if (!getbit(ent_mask, d)) continue;
            bk = d >> 9;
        } else {
            int r = ui_row[e - e_kg];
            if (!getbit(node_mask, r)) continue;
            bk = NB_KG + (r >> 8);
        }
        atomicAdd(&h[bk], 1);
    }
    __syncthreads();
    for (int i = threadIdx.x; i < NB_TOT; i += 256)
        if (h[i]) atomicAdd(&bcnt[i], h[i]);
}

// ---------------------------------------------------------------------------
// Pass B: exclusive scan of bucket counts. boff[NB] = total KEPT edges.
// ---------------------------------------------------------------------------
__global__ __launch_bounds__(256) void bucket_scan(const int* __restrict__ bcnt,
                                                   int* __restrict__ boff_kg,
                                                   int* __restrict__ boff_ui,
                                                   int* __restrict__ bcur) {
    __shared__ int sh[1024];
    int t = threadIdx.x;
    for (int seg = 0; seg < 2; seg++) {
        int NB = seg ? NB_UI : NB_KG;
        const int* src = bcnt + (seg ? NB_KG : 0);
        int idx[4] = { t, t + 256, t + 512, t + 768 };
        int v[4];
        #pragma unroll
        for (int q = 0; q < 4; q++) {
            v[q] = (idx[q] < NB) ? src[idx[q]] : 0;
            sh[idx[q]] = v[q];
        }
        __syncthreads();
        for (int o = 1; o < 1024; o <<= 1) {
            int a[4];
            #pragma unroll
            for (int q = 0; q < 4; q++) a[q] = (idx[q] >= o) ? sh[idx[q] - o] : 0;
            __syncthreads();
            #pragma unroll
            for (int q = 0; q < 4; q++) sh[idx[q]] += a[q];
            __syncthreads();
        }
        int* boff = seg ? boff_ui : boff_kg;
        int  base = seg ? NB_KG : 0;
        #pragma unroll
        for (int q = 0; q < 4; q++) {
            if (idx[q] < NB) {
                int ex = sh[idx[q]] - v[q];
                boff[idx[q]] = ex;
                bcur[base + idx[q]] = ex;
                if (idx[q] == NB - 1) boff[NB] = sh[idx[q]];
            }
        }
        __syncthreads();
    }
}

// ---------------------------------------------------------------------------
// Pass C: scatter KEPT edges into bucket regions.
// KG rec: src(18) | rel<<18 (5) | dst_local<<23 (9)
// UI rec: col(18) | row_local<<18 (8); parallel uval[] carries ui_vals[e].
// ---------------------------------------------------------------------------
__global__ __launch_bounds__(256) void bucket_scatter(const int* __restrict__ kg_src,
                                                      const int* __restrict__ kg_dst,
                                                      const int* __restrict__ kg_rel,
                                                      const int* __restrict__ ui_row,
                                                      const int* __restrict__ ui_col,
                                                      const float* __restrict__ ui_vals,
                                                      const unsigned* __restrict__ ent_mask,
                                                      const unsigned* __restrict__ node_mask,
                                                      int* __restrict__ bcur,
                                                      unsigned int* __restrict__ kgrec,
                                                      int* __restrict__ uirec,
                                                      float* __restrict__ uval,
                                                      int e_kg, int e_ui) {
    __shared__ int h[NB_TOT];
    __shared__ int lbase[NB_TOT];
    int n = e_kg + e_ui;
    int nchunks = (n + 4095) >> 12;
    int tid = threadIdx.x;
    for (int c = blockIdx.x; c < nchunks; c += gridDim.x) {
        int base = c << 12;
        for (int i = tid; i < NB_TOT; i += 256) h[i] = 0;
        __syncthreads();
        unsigned int rec[16];
        float val[16];
        int bk[16];
        #pragma unroll
        for (int j = 0; j < 16; j++) {
            int e = base + j * 256 + tid;
            bk[j] = -1;
            if (e < n) {
                if (e < e_kg) {
                    int d = kg_dst[e];
                    if (getbit(ent_mask, d)) {
                        bk[j]  = d >> 9;
                        rec[j] = (unsigned int)kg_src[e] | ((unsigned int)kg_rel[e] << 18)
                                 | ((unsigned int)(d & 511) << 23);
                        atomicAdd(&h[bk[j]], 1);
                    }
                } else {
                    int i2 = e - e_kg;
                    int r  = ui_row[i2];
                    if (getbit(node_mask, r)) {
                        bk[j]  = NB_KG + (r >> 8);
                        rec[j] = (unsigned int)ui_col[i2] | ((unsigned int)(r & 255) << 18);
                        val[j] = ui_vals[i2];
                        atomicAdd(&h[bk[j]], 1);
                    }
                }
            }
        }
        __syncthreads();
        for (int i = tid; i < NB_TOT; i += 256) {
            int cc = h[i];
            lbase[i] = cc ? atomicAdd(&bcur[i], cc) : 0;
        }
        __syncthreads();
        #pragma unroll
        for (int j = 0; j < 16; j++) {
            if (bk[j] >= 0) {
                int pos = atomicAdd(&lbase[bk[j]], 1);
                if (bk[j] < NB_KG) kgrec[pos] = rec[j];
                else               { uirec[pos] = (int)rec[j]; uval[pos] = val[j]; }
            }
        }
        __syncthreads();
    }
}

// ---------------------------------------------------------------------------
// Pass D: one block per bucket. LDS counting-sort of KEPT records; emits CSR
// off[] and sorted records (+reordered uval for UI).
// ---------------------------------------------------------------------------
__global__ __launch_bounds__(256) void bucket_finalize(const int* __restrict__ boff_kg,
                                                       const int* __restrict__ boff_ui,
                                                       unsigned int* __restrict__ kgrec,
                                                       int* __restrict__ uirec,
                                                       float* __restrict__ uval,
                                                       int* __restrict__ off_kg,
                                                       int* __restrict__ off_ui) {
    __shared__ unsigned int rec[CAPD];
    __shared__ float fval[CAPD];
    __shared__ int hist[512];
    bool iskg = blockIdx.x < NB_KG;
    int  b    = iskg ? blockIdx.x : blockIdx.x - NB_KG;
    const int* boff = iskg ? boff_kg : boff_ui;
    int ebeg = boff[b], eend = boff[b + 1];
    int ne   = min(eend - ebeg, CAPD);
    int key_base = iskg ? (b << 9) : (b << 8);
    int nkeys = iskg ? min(512, N_ENT - key_base) : min(256, N_NODES - key_base);
    int SH = iskg ? 23 : 18;
    int tid = threadIdx.x;

    for (int i = tid; i < ne; i += 256) {
        if (iskg) rec[i] = kgrec[ebeg + i];
        else { rec[i] = (unsigned int)uirec[ebeg + i]; fval[i] = uval[ebeg + i]; }
    }
    for (int i = tid; i < 512; i += 256) hist[i] = 0;
    __syncthreads();
    for (int i = tid; i < ne; i += 256)
        atomicAdd(&hist[rec[i] >> SH], 1);
    __syncthreads();
    int i0 = tid, i1 = tid + 256;
    int v0 = hist[i0], v1 = hist[i1];
    __syncthreads();
    for (int o = 1; o < 512; o <<= 1) {
        int a0 = (i0 >= o) ? hist[i0 - o] : 0;
        int a1 = (i1 >= o) ? hist[i1 - o] : 0;
        __syncthreads();
        hist[i0] += a0; hist[i1] += a1;
        __syncthreads();
    }
    int e0 = hist[i0] - v0, e1 = hist[i1] - v1;
    __syncthreads();
    hist[i0] = e0; hist[i1] = e1;
    int* offg = iskg ? off_kg : off_ui;
    if (i0 < nkeys) offg[key_base + i0] = ebeg + e0;
    if (i1 < nkeys) offg[key_base + i1] = ebeg + e1;
    if (blockIdx.x == 0 && tid == 0) {
        off_kg[N_ENT]   = boff_kg[NB_KG];
        off_ui[N_NODES] = boff_ui[NB_UI];
    }
    __syncthreads();
    for (int i = tid; i < ne; i += 256) {
        unsigned int r = rec[i];
        int k = r >> SH;
        int slot = atomicAdd(&hist[k], 1);
        if (iskg) kgrec[ebeg + slot] = r & 0x7FFFFFu;
        else      { uirec[ebeg + slot] = (int)(r & 0x3FFFFu); uval[ebeg + slot] = fval[i]; }
    }
}

// ---------------------------------------------------------------------------
// kgagg_build: ONE WAVE PER NODE — quarter-wave gather form.
// Each y16 row (128B) is read by 16 lanes x uint2 (8B = 4 bf16/lane), so one
// load instruction serves 4 edges (64 lanes = 4 rows). Halves load-instr and
// address-VALU per edge vs the old 32-lane x 4B form (kernel was VALU-bound:
// VALUBusy 52%, HBM 24%). Gate lookup becomes one float4.
// ---------------------------------------------------------------------------
__global__ __launch_bounds__(256) void kgagg_build(const int* __restrict__ off,
                                                   const unsigned int* __restrict__ packed,
                                                   const unsigned short* __restrict__ y16,
                                                   const float* __restrict__ entity_emb,
                                                   const float* __restrict__ user_emb,
                                                   const int* __restrict__ i2e,
                                                   const float4* __restrict__ gate4,
                                                   float* __restrict__ all_emb,
                                                   unsigned short* __restrict__ all16) {
    int lane = threadIdx.x & 63;
    int w = (blockIdx.x * 256 + threadIdx.x) >> 6;
    if (w >= N_NODES) return;
    int ql      = lane & 15;   // 16-lane slot within row (dims 4ql..4ql+3)
    int quarter = lane >> 4;   // which edge of a 4-edge group

    if (w < N_USERS) {                    // user row: bf16 copy only
        if (quarter == 0) {
            float4 v = ((const float4*)user_emb)[(long)w * 16 + ql];
            ((uint2*)all16)[(long)w * 16 + ql] =
                make_uint2((unsigned)f2bf(v.x) | ((unsigned)f2bf(v.y) << 16),
                           (unsigned)f2bf(v.z) | ((unsigned)f2bf(v.w) << 16));
        }
        return;
    }

    int ent = __builtin_amdgcn_readfirstlane(i2e[w - N_USERS]);
    const uint2* y2 = (const uint2*)y16;
    int beg = __builtin_amdgcn_readfirstlane(off[ent]);
    int end = __builtin_amdgcn_readfirstlane(off[ent + 1]);
    float a0 = 0.f, a1 = 0.f, a2 = 0.f, a3 = 0.f;
    float b0 = 0.f, b1 = 0.f, b2 = 0.f, b3 = 0.f;
    int p = beg;
    for (; p + 8 <= end; p += 8) {
        unsigned pk0 = packed[p + quarter];
        unsigned pk1 = packed[p + 4 + quarter];
        uint2 v0 = y2[(long)(pk0 & 0x3FFFF) * 16 + ql];
        uint2 v1 = y2[(long)(pk1 & 0x3FFFF) * 16 + ql];
        float4 g0 = gate4[(pk0 >> 18) * 16 + ql];
        float4 g1 = gate4[(pk1 >> 18) * 16 + ql];
        a0 += bf_lo(v0.x) * g0.x;  a1 += bf_hi(v0.x) * g0.y;
        a2 += bf_lo(v0.y) * g0.z;  a3 += bf_hi(v0.y) * g0.w;
        b0 += bf_lo(v1.x) * g1.x;  b1 += bf_hi(v1.x) * g1.y;
        b2 += bf_lo(v1.y) * g1.z;  b3 += bf_hi(v1.y) * g1.w;
    }
    if (p + 4 <= end) {
        unsigned pk = packed[p + quarter];
        uint2 v = y2[(long)(pk & 0x3FFFF) * 16 + ql];
        float4 g = gate4[(pk >> 18) * 16 + ql];
        a0 += bf_lo(v.x) * g.x;  a1 += bf_hi(v.x) * g.y;
        a2 += bf_lo(v.y) * g.z;  a3 += bf_hi(v.y) * g.w;
        p += 4;
    }
    if (p + quarter < end) {
        unsigned pk = packed[p + quarter];
        uint2 v = y2[(long)(pk & 0x3FFFF) * 16 + ql];
        float4 g = gate4[(pk >> 18) * 16 + ql];
        b0 += bf_lo(v.x) * g.x;  b1 += bf_hi(v.x) * g.y;
        b2 += bf_lo(v.y) * g.z;  b3 += bf_hi(v.y) * g.w;
    }
    a0 += b0; a1 += b1; a2 += b2; a3 += b3;
    // merge quarters: lanes L, L+16, L+32, L+48 hold the same dims
    a0 += __shfl_xor(a0, 16);  a0 += __shfl_xor(a0, 32);
    a1 += __shfl_xor(a1, 16);  a1 += __shfl_xor(a1, 32);
    a2 += __shfl_xor(a2, 16);  a2 += __shfl_xor(a2, 32);
    a3 += __shfl_xor(a3, 16);  a3 += __shfl_xor(a3, 32);

    float deg = fmaxf((float)(end - beg), 1.0f);
    float4 xv = ((const float4*)entity_emb)[(long)ent * 16 + ql];
    float v0 = a0 / deg + xv.x;
    float v1 = a1 / deg + xv.y;
    float v2 = a2 / deg + xv.z;
    float v3 = a3 / deg + xv.w;
    v0 = (v0 > 0.0f) ? v0 : (__expf(v0) - 1.0f);
    v1 = (v1 > 0.0f) ? v1 : (__expf(v1) - 1.0f);
    v2 = (v2 > 0.0f) ? v2 : (__expf(v2) - 1.0f);
    v3 = (v3 > 0.0f) ? v3 : (__expf(v3) - 1.0f);
    float ss = v0 * v0 + v1 * v1 + v2 * v2 + v3 * v3;
    ss += __shfl_xor(ss, 1);
    ss += __shfl_xor(ss, 2);
    ss += __shfl_xor(ss, 4);
    ss += __shfl_xor(ss, 8);
    float inv = 1.0f / fmaxf(sqrtf(ss), 1e-12f);
    if (quarter == 0) {
        float r0 = v0 * inv, r1 = v1 * inv, r2 = v2 * inv, r3 = v3 * inv;
        ((float4*)all_emb)[(long)w * 16 + ql] = make_float4(r0, r1, r2, r3);
        ((uint2*)all16)[(long)w * 16 + ql] =
            make_uint2((unsigned)f2bf(r0) | ((unsigned)f2bf(r1) << 16),
                       (unsigned)f2bf(r2) | ((unsigned)f2bf(r3) << 16));
    }
}

// ---------------------------------------------------------------------------
// ui_aggregate_s: one wave per SAMPLE ROW (3B waves), quarter-wave gather
// (same transform as kgagg_build).
// ---------------------------------------------------------------------------
__global__ __launch_bounds__(256) void ui_aggregate_s(const int* __restrict__ off,
                                                      const int* __restrict__ colrec,
                                                      const float* __restrict__ uval,
                                                      const float* __restrict__ all_emb,
                                                      const float* __restrict__ user_emb,
                                                      const unsigned short* __restrict__ all16,
                                                      const int* __restrict__ u,
                                                      const int* __restrict__ ipos,
                                                      const int* __restrict__ ineg,
                                                      float* __restrict__ final_emb, int B) {
    const uint2* a2p = (const uint2*)all16;
    int lane = threadIdx.x & 63;
    int ql      = lane & 15;
    int quarter = lane >> 4;
    int w = (blockIdx.x * 256 + threadIdx.x) >> 6;
    if (w >= 3 * B) return;
    int r;
    if (w < B)          r = u[w];
    else if (w < 2 * B) r = N_USERS + ipos[w - B];
    else                r = N_USERS + ineg[w - 2 * B];
    r = __builtin_amdgcn_readfirstlane(r);

    int beg = __builtin_amdgcn_readfirstlane(off[r]);
    int end = __builtin_amdgcn_readfirstlane(off[r + 1]);
    float a0 = 0.f, a1 = 0.f, a2 = 0.f, a3 = 0.f;
    float b0 = 0.f, b1 = 0.f, b2 = 0.f, b3 = 0.f;
    int p = beg;
    for (; p + 8 <= end; p += 8) {
        int   c0 = colrec[p + quarter];
        int   c1 = colrec[p + 4 + quarter];
        float d0 = uval[p + quarter];
        float d1 = uval[p + 4 + quarter];
        uint2 v0 = a2p[(long)c0 * 16 + ql];
        uint2 v1 = a2p[(long)c1 * 16 + ql];
        a0 += d0 * bf_lo(v0.x);  a1 += d0 * bf_hi(v0.x);
        a2 += d0 * bf_lo(v0.y);  a3 += d0 * bf_hi(v0.y);
        b0 += d1 * bf_lo(v1.x);  b1 += d1 * bf_hi(v1.x);
        b2 += d1 * bf_lo(v1.y);  b3 += d1 * bf_hi(v1.y);
    }
    if (p + 4 <= end) {
        int   c = colrec[p + quarter];
        float d = uval[p + quarter];
        uint2 v = a2p[(long)c * 16 + ql];
        a0 += d * bf_lo(v.x);  a1 += d * bf_hi(v.x);
        a2 += d * bf_lo(v.y);  a3 += d * bf_hi(v.y);
        p += 4;
    }
    if (p + quarter < end) {
        int   c = colrec[p + quarter];
        float d = uval[p + quarter];
        uint2 v = a2p[(long)c * 16 + ql];
        b0 += d * bf_lo(v.x);  b1 += d * bf_hi(v.x);
        b2 += d * bf_lo(v.y);  b3 += d * bf_hi(v.y);
    }
    a0 += b0; a1 += b1; a2 += b2; a3 += b3;
    a0 += __shfl_xor(a0, 16);  a0 += __shfl_xor(a0, 32);
    a1 += __shfl_xor(a1, 16);  a1 += __shfl_xor(a1, 32);
    a2 += __shfl_xor(a2, 16);  a2 += __shfl_xor(a2, 32);
    a3 += __shfl_xor(a3, 16);  a3 += __shfl_xor(a3, 32);
    if (quarter == 0) {
        float4 ae = (r < N_USERS)
            ? ((const float4*)user_emb)[(long)r * 16 + ql]
            : ((const float4*)all_emb)[(long)r * 16 + ql];
        ((float4*)final_emb)[(long)r * 16 + ql] =
            make_float4(0.5f * (ae.x + a0), 0.5f * (ae.y + a1),
                        0.5f * (ae.z + a2), 0.5f * (ae.w + a3));
    }
}

// ---------------------------------------------------------------------------
// Epilogue (intent folded in): one wave per sample.
// ---------------------------------------------------------------------------
__global__ void final_kernel(const int* __restrict__ u, const int* __restrict__ ipos,
                             const int* __restrict__ ineg,
                             const float* __restrict__ final_emb,
                             const float* __restrict__ all_emb,
                             const float* __restrict__ rw, const float* __restrict__ rb,
                             const float* __restrict__ iw, const float* __restrict__ rel_emb,
                             float* __restrict__ out, int B) {
    __shared__ float sh_intent[128];
    if (threadIdx.x < 64) {
        int j = threadIdx.x;
        for (int k = 0; k < 2; k++) {
            float m = -1e30f;
            for (int r = 0; r < N_REL; r++) m = fmaxf(m, iw[k * N_REL + r]);
            float Z = 0.f, acc = 0.f;
            for (int r = 0; r < N_REL; r++) {
                float e = __expf(iw[k * N_REL + r] - m);
                Z += e;
                acc += e * rel_emb[r * 64 + j];
            }
            sh_intent[k * 64 + j] = acc / Z;
        }
    }
    __syncthreads();
    int lane = threadIdx.x & 63;
    int wave = (blockIdx.x * blockDim.x + threadIdx.x) >> 6;
    int nw   = (gridDim.x * blockDim.x) >> 6;
    for (int b = wave; b < B; b += nw) {
        int uu = u[b];
        float up = final_emb[(long)uu * 64 + lane];
        float l0 = up * rw[lane];
        float l1 = up * rw[64 + lane];
        #pragma unroll
        for (int o = 32; o; o >>= 1) {
            l0 += __shfl_xor(l0, o);
            l1 += __shfl_xor(l1, o);
        }
        l0 += rb[0]; l1 += rb[1];
        float m  = fmaxf(l0, l1);
        float e0 = __expf(l0 - m), e1 = __expf(l1 - m);
        float inv = 1.0f / (e0 + e1);
        float p0 = e0 * inv, p1 = e1 * inv;
        float ue = up + p0 * sh_intent[lane] + p1 * sh_intent[64 + lane];

        int it = ipos[b];
        long rr = (long)(N_USERS + it) * 64 + lane;
        float ie = final_emb[rr] + all_emb[rr];
        float dp = ue * ie;
        #pragma unroll
        for (int o = 32; o; o >>= 1) dp += __shfl_xor(dp, o);
        if (lane == 0) out[b] = dp;

        it = ineg[b];
        rr = (long)(N_USERS + it) * 64 + lane;
        ie = final_emb[rr] + all_emb[rr];
        dp = ue * ie;
        #pragma unroll
        for (int o = 32; o; o >>= 1) dp += __shfl_xor(dp, o);
        if (lane == 0) out[B + b] = dp;
    }
}

extern "C" void kernel_launch(void* const* d_in, const int* in_sizes, int n_in,
                              void* d_out, int out_size, void* d_ws, size_t ws_size,
                              hipStream_t stream) {
    const int*   u          = (const int*)  d_in[0];
    const int*   ipos       = (const int*)  d_in[1];
    const int*   ineg       = (const int*)  d_in[2];
    const float* user_emb   = (const float*)d_in[3];
    const float* entity_emb = (const float*)d_in[4];
    const float* rel_emb    = (const float*)d_in[5];
    const float* iw         = (const float*)d_in[6];
    const float* rw         = (const float*)d_in[7];
    const float* rb         = (const float*)d_in[8];
    const float* kgw        = (const float*)d_in[9];
    const float* ui_vals    = (const float*)d_in[10];
    const int*   i2e        = (const int*)  d_in[11];
    const int*   kg_src     = (const int*)  d_in[12];
    const int*   kg_dst     = (const int*)  d_in[13];
    const int*   kg_rel     = (const int*)  d_in[14];
    const int*   ui_row     = (const int*)  d_in[15];
    const int*   ui_col     = (const int*)  d_in[16];
    float*       out        = (float*)d_out;

    int B    = in_sizes[0];
    int e_kg = in_sizes[12];
    int e_ui = in_sizes[15];

    // ---------------- workspace layout (bytes) ----------------
    char* ws = (char*)d_ws;
    unsigned short* y16       = (unsigned short*)(ws + 0);        // 25.6 MB
    float*          all_emb   = (float*)(ws + 25600000);          // 38.4 MB
    unsigned short* all16     = (unsigned short*)(ws + 64000000); // 19.2 MB
    float*          final_emb = (float*)(ws + 83200000);          // 38.4 MB (sparse use)
    unsigned int*   kgrec     = (unsigned int*)(ws + 121600000);  // 8 MB
    int*            uirec     = (int*)(ws + 129600000);           // 4 MB
    float*          uval      = (float*)(ws + 133600000);         // 4 MB
    int*            off_kg    = (int*)(ws + 137600000);           // 200001 ints
    int*            off_ui    = (int*)(ws + 138400256);           // 150001 ints
    unsigned*       ent_mask  = (unsigned*)(ws + 139000512);      // 25088 B (200K bits)
    unsigned*       node_mask = (unsigned*)(ws + 139025600);      // 18752 B (150K bits)
    int*            bcnt      = (int*)(ws + 139600512);           // 977 ints
    int*            boff_kg   = (int*)(ws + 139604480);           // 392 ints
    int*            boff_ui   = (int*)(ws + 139606272);           // 587 ints
    int*            bcur      = (int*)(ws + 139608704);           // 977 ints
    float2*         gateg     = (float2*)(ws + 139612672);        // 8 KB gate table

    hipMemsetAsync(ent_mask, 0, 25088 + 18752, stream);   // masks contiguous
    build_masks    <<<512, 256, 0, stream>>>(i2e, u, ipos, ineg, ent_mask, node_mask,
                                             bcnt, B);
    bucket_hist    <<<1024, 256, 0, stream>>>(kg_dst, ui_row, ent_mask, node_mask,
                                              rel_emb, gateg, bcnt, e_kg, e_ui);
    bucket_scan    <<<1,   256, 0, stream>>>(bcnt, boff_kg, boff_ui, bcur);
    bucket_scatter <<<512, 256, 0, stream>>>(kg_src, kg_dst, kg_rel, ui_row, ui_col,
                                             ui_vals, ent_mask, node_mask,
                                             bcur, kgrec, uirec, uval, e_kg, e_ui);
    bucket_finalize<<<NB_TOT, 256, 0, stream>>>(boff_kg, boff_ui, kgrec, uirec, uval,
                                                off_kg, off_ui);

    ent_matmul <<<(N_ENT + 127) / 128, 128, 0, stream>>>(entity_emb, kgw, y16, N_ENT);
    kgagg_build<<<(N_NODES * 64 + 255) / 256, 256, 0, stream>>>(
        off_kg, kgrec, y16, entity_emb, user_emb, i2e, (const float4*)gateg,
        all_emb, all16);
    ui_aggregate_s<<<(3 * B * 64 + 255) / 256, 256, 0, stream>>>(
        off_ui, uirec, uval, all_emb, user_emb, all16, u, ipos, ineg, final_emb, B);
    final_kernel<<<256, 256, 0, stream>>>(u, ipos, ineg, final_emb, all_emb,
                                          rw, rb, iw, rel_emb, out, B);
}

// Round 5
// 364.709 us; speedup vs baseline: 1.0691x; 1.0248x over previous
//
#include <hip/hip_runtime.h>
#include <math.h>

#define N_USERS 50000
#define N_ITEMS 100000
#define N_ENT   200000
#define N_NODES (N_USERS + N_ITEMS)
#define N_REL   32
#define DIM     64

#define NB_KG  391          // KG buckets: dst>>9 (512 keys each)
#define NB_UI  586          // UI buckets: row>>8 (256 keys each)
#define NB_TOT (NB_KG + NB_UI)   // 977
#define CAPD   4096         // max KEPT edges per bucket (post-filter)

__device__ __forceinline__ unsigned short f2bf(float f) {   // RNE f32->bf16
    unsigned u = __float_as_uint(f);
    u += 0x7FFFu + ((u >> 16) & 1u);
    return (unsigned short)(u >> 16);
}
__device__ __forceinline__ float bf_lo(unsigned v) { return __uint_as_float(v << 16); }
__device__ __forceinline__ float bf_hi(unsigned v) { return __uint_as_float(v & 0xFFFF0000u); }
__device__ __forceinline__ int getbit(const unsigned* m, int i) {
    return (m[i >> 5] >> (i & 31)) & 1;
}

// ---------------------------------------------------------------------------
// ent_matmul: y16 = bf16(x @ W^T), register-tiled LDS GEMM (R7 form).
// xt is [64 k][128 rows + 4 pad] — do NOT shrink the second dim below 128
// (R4 regression: [64][68] truncated the row dim and corrupted the tile).
// ---------------------------------------------------------------------------
__global__ __launch_bounds__(128) void ent_matmul(const float* __restrict__ x,
                                                  const float* __restrict__ w,
                                                  unsigned short* __restrict__ y16,
                                                  int n_ent) {
    __shared__ float xt[64][132];
    __shared__ float wt[64][68];
    int tid  = threadIdx.x;
    int base = blockIdx.x * 128;

    #pragma unroll
    for (int q = 0; q < 8; q++) {
        int idx = q * 128 + tid;
        int j = idx >> 4, k4 = idx & 15;
        float4 v = ((const float4*)w)[idx];
        wt[4 * k4 + 0][j] = v.x;
        wt[4 * k4 + 1][j] = v.y;
        wt[4 * k4 + 2][j] = v.z;
        wt[4 * k4 + 3][j] = v.w;
    }
    #pragma unroll
    for (int q = 0; q < 16; q++) {
        int idx = q * 128 + tid;
        int r = idx >> 4, k4 = idx & 15;
        int gr = base + r;
        if (gr < n_ent) {
            float4 v = ((const float4*)x)[(long)gr * 16 + k4];
            xt[4 * k4 + 0][r] = v.x;
            xt[4 * k4 + 1][r] = v.y;
            xt[4 * k4 + 2][r] = v.z;
            xt[4 * k4 + 3][r] = v.w;
        }
    }
    __syncthreads();

    int j0 = (tid & 7) * 8;
    int r0 = (tid >> 3) * 8;
    float acc[8][8];
    #pragma unroll
    for (int i = 0; i < 8; i++)
        #pragma unroll
        for (int j = 0; j < 8; j++) acc[i][j] = 0.f;

    #pragma unroll 4
    for (int k = 0; k < 64; k++) {
        float4 xa = *(const float4*)&xt[k][r0];
        float4 xb = *(const float4*)&xt[k][r0 + 4];
        float4 wa = *(const float4*)&wt[k][j0];
        float4 wb = *(const float4*)&wt[k][j0 + 4];
        float xr[8] = {xa.x, xa.y, xa.z, xa.w, xb.x, xb.y, xb.z, xb.w};
        float wr[8] = {wa.x, wa.y, wa.z, wa.w, wb.x, wb.y, wb.z, wb.w};
        #pragma unroll
        for (int i = 0; i < 8; i++)
            #pragma unroll
            for (int j = 0; j < 8; j++)
                acc[i][j] += xr[i] * wr[j];
    }

    #pragma unroll
    for (int i = 0; i < 8; i++) {
        int gr = base + r0 + i;
        if (gr < n_ent) {
            uint4 o;
            o.x = (unsigned)f2bf(acc[i][0]) | ((unsigned)f2bf(acc[i][1]) << 16);
            o.y = (unsigned)f2bf(acc[i][2]) | ((unsigned)f2bf(acc[i][3]) << 16);
            o.z = (unsigned)f2bf(acc[i][4]) | ((unsigned)f2bf(acc[i][5]) << 16);
            o.w = (unsigned)f2bf(acc[i][6]) | ((unsigned)f2bf(acc[i][7]) << 16);
            *(uint4*)&y16[(long)gr * 64 + j0] = o;
        }
    }
}

// ---------------------------------------------------------------------------
// build_masks: membership bitmaps + zero bcnt.
// ---------------------------------------------------------------------------
__global__ __launch_bounds__(256) void build_masks(const int* __restrict__ i2e,
                                                   const int* __restrict__ u,
                                                   const int* __restrict__ ipos,
                                                   const int* __restrict__ ineg,
                                                   unsigned* __restrict__ ent_mask,
                                                   unsigned* __restrict__ node_mask,
                                                   int* __restrict__ bcnt,
                                                   int B) {
    int t = blockIdx.x * 256 + threadIdx.x;
    int stride = gridDim.x * 256;
    for (int i = threadIdx.x; i < NB_TOT; i += 256) bcnt[i] = 0;
    for (int i = t; i < N_ITEMS; i += stride) {
        int e = i2e[i];
        atomicOr(&ent_mask[e >> 5], 1u << (e & 31));
    }
    for (int i = t; i < 3 * B; i += stride) {
        int r = (i < B) ? u[i]
              : (i < 2 * B) ? N_USERS + ipos[i - B]
                            : N_USERS + ineg[i - 2 * B];
        atomicOr(&node_mask[r >> 5], 1u << (r & 31));
    }
}

// ---------------------------------------------------------------------------
// Pass A: per-block LDS bucket histogram over KEPT edges only.
// Block 0 additionally precomputes the sigmoid gate table ONCE into gateg.
// ---------------------------------------------------------------------------
__global__ __launch_bounds__(256) void bucket_hist(const int* __restrict__ kg_dst,
                                                   const int* __restrict__ ui_row,
                                                   const unsigned* __restrict__ ent_mask,
                                                   const unsigned* __restrict__ node_mask,
                                                   const float* __restrict__ rel_emb,
                                                   float2* __restrict__ gateg,
                                                   int* __restrict__ bcnt,
                                                   int e_kg, int e_ui) {
    __shared__ int h[NB_TOT];
    for (int i = threadIdx.x; i < NB_TOT; i += 256) h[i] = 0;
    __syncthreads();
    if (blockIdx.x == 0) {
        for (int idx = threadIdx.x; idx < N_REL * 32; idx += 256) {
            int rel = idx >> 5, hl2 = idx & 31;
            float g0 = 1.0f / (1.0f + __expf(-rel_emb[rel * 64 + 2 * hl2]));
            float g1 = 1.0f / (1.0f + __expf(-rel_emb[rel * 64 + 2 * hl2 + 1]));
            gateg[idx] = make_float2(g0, g1);
        }
    }
    int n = e_kg + e_ui;
    int t = blockIdx.x * 256 + threadIdx.x;
    int stride = gridDim.x * 256;
    for (int e = t; e < n; e += stride) {
        int bk;
        if (e < e_kg) {
            int d = kg_dst[e];
            if (!getbit(ent_mask, d)) continue;
            bk = d >> 9;
        } else {
            int r = ui_row[e - e_kg];
            if (!getbit(node_mask, r)) continue;
            bk = NB_KG + (r >> 8);
        }
        atomicAdd(&h[bk], 1);
    }
    __syncthreads();
    for (int i = threadIdx.x; i < NB_TOT; i += 256)
        if (h[i]) atomicAdd(&bcnt[i], h[i]);
}

// ---------------------------------------------------------------------------
// Pass B: exclusive scan of bucket counts. boff[NB] = total KEPT edges.
// ---------------------------------------------------------------------------
__global__ __launch_bounds__(256) void bucket_scan(const int* __restrict__ bcnt,
                                                   int* __restrict__ boff_kg,
                                                   int* __restrict__ boff_ui,
                                                   int* __restrict__ bcur) {
    __shared__ int sh[1024];
    int t = threadIdx.x;
    for (int seg = 0; seg < 2; seg++) {
        int NB = seg ? NB_UI : NB_KG;
        const int* src = bcnt + (seg ? NB_KG : 0);
        int idx[4] = { t, t + 256, t + 512, t + 768 };
        int v[4];
        #pragma unroll
        for (int q = 0; q < 4; q++) {
            v[q] = (idx[q] < NB) ? src[idx[q]] : 0;
            sh[idx[q]] = v[q];
        }
        __syncthreads();
        for (int o = 1; o < 1024; o <<= 1) {
            int a[4];
            #pragma unroll
            for (int q = 0; q < 4; q++) a[q] = (idx[q] >= o) ? sh[idx[q] - o] : 0;
            __syncthreads();
            #pragma unroll
            for (int q = 0; q < 4; q++) sh[idx[q]] += a[q];
            __syncthreads();
        }
        int* boff = seg ? boff_ui : boff_kg;
        int  base = seg ? NB_KG : 0;
        #pragma unroll
        for (int q = 0; q < 4; q++) {
            if (idx[q] < NB) {
                int ex = sh[idx[q]] - v[q];
                boff[idx[q]] = ex;
                bcur[base + idx[q]] = ex;
                if (idx[q] == NB - 1) boff[NB] = sh[idx[q]];
            }
        }
        __syncthreads();
    }
}

// ---------------------------------------------------------------------------
// Pass C: scatter KEPT edges into bucket regions.
// ---------------------------------------------------------------------------
__global__ __launch_bounds__(256) void bucket_scatter(const int* __restrict__ kg_src,
                                                      const int* __restrict__ kg_dst,
                                                      const int* __restrict__ kg_rel,
                                                      const int* __restrict__ ui_row,
                                                      const int* __restrict__ ui_col,
                                                      const float* __restrict__ ui_vals,
                                                      const unsigned* __restrict__ ent_mask,
                                                      const unsigned* __restrict__ node_mask,
                                                      int* __restrict__ bcur,
                                                      unsigned int* __restrict__ kgrec,
                                                      int* __restrict__ uirec,
                                                      float* __restrict__ uval,
                                                      int e_kg, int e_ui) {
    __shared__ int h[NB_TOT];
    __shared__ int lbase[NB_TOT];
    int n = e_kg + e_ui;
    int nchunks = (n + 4095) >> 12;
    int tid = threadIdx.x;
    for (int c = blockIdx.x; c < nchunks; c += gridDim.x) {
        int base = c << 12;
        for (int i = tid; i < NB_TOT; i += 256) h[i] = 0;
        __syncthreads();
        unsigned int rec[16];
        float val[16];
        int bk[16];
        #pragma unroll
        for (int j = 0; j < 16; j++) {
            int e = base + j * 256 + tid;
            bk[j] = -1;
            if (e < n) {
                if (e < e_kg) {
                    int d = kg_dst[e];
                    if (getbit(ent_mask, d)) {
                        bk[j]  = d >> 9;
                        rec[j] = (unsigned int)kg_src[e] | ((unsigned int)kg_rel[e] << 18)
                                 | ((unsigned int)(d & 511) << 23);
                        atomicAdd(&h[bk[j]], 1);
                    }
                } else {
                    int i2 = e - e_kg;
                    int r  = ui_row[i2];
                    if (getbit(node_mask, r)) {
                        bk[j]  = NB_KG + (r >> 8);
                        rec[j] = (unsigned int)ui_col[i2] | ((unsigned int)(r & 255) << 18);
                        val[j] = ui_vals[i2];
                        atomicAdd(&h[bk[j]], 1);
                    }
                }
            }
        }
        __syncthreads();
        for (int i = tid; i < NB_TOT; i += 256) {
            int cc = h[i];
            lbase[i] = cc ? atomicAdd(&bcur[i], cc) : 0;
        }
        __syncthreads();
        #pragma unroll
        for (int j = 0; j < 16; j++) {
            if (bk[j] >= 0) {
                int pos = atomicAdd(&lbase[bk[j]], 1);
                if (bk[j] < NB_KG) kgrec[pos] = rec[j];
                else               { uirec[pos] = (int)rec[j]; uval[pos] = val[j]; }
            }
        }
        __syncthreads();
    }
}

// ---------------------------------------------------------------------------
// Pass D: one block per bucket. LDS counting-sort of KEPT records.
// ---------------------------------------------------------------------------
__global__ __launch_bounds__(256) void bucket_finalize(const int* __restrict__ boff_kg,
                                                       const int* __restrict__ boff_ui,
                                                       unsigned int* __restrict__ kgrec,
                                                       int* __restrict__ uirec,
                                                       float* __restrict__ uval,
                                                       int* __restrict__ off_kg,
                                                       int* __restrict__ off_ui) {
    __shared__ unsigned int rec[CAPD];
    __shared__ float fval[CAPD];
    __shared__ int hist[512];
    bool iskg = blockIdx.x < NB_KG;
    int  b    = iskg ? blockIdx.x : blockIdx.x - NB_KG;
    const int* boff = iskg ? boff_kg : boff_ui;
    int ebeg = boff[b], eend = boff[b + 1];
    int ne   = min(eend - ebeg, CAPD);
    int key_base = iskg ? (b << 9) : (b << 8);
    int nkeys = iskg ? min(512, N_ENT - key_base) : min(256, N_NODES - key_base);
    int SH = iskg ? 23 : 18;
    int tid = threadIdx.x;

    for (int i = tid; i < ne; i += 256) {
        if (iskg) rec[i] = kgrec[ebeg + i];
        else { rec[i] = (unsigned int)uirec[ebeg + i]; fval[i] = uval[ebeg + i]; }
    }
    for (int i = tid; i < 512; i += 256) hist[i] = 0;
    __syncthreads();
    for (int i = tid; i < ne; i += 256)
        atomicAdd(&hist[rec[i] >> SH], 1);
    __syncthreads();
    int i0 = tid, i1 = tid + 256;
    int v0 = hist[i0], v1 = hist[i1];
    __syncthreads();
    for (int o = 1; o < 512; o <<= 1) {
        int a0 = (i0 >= o) ? hist[i0 - o] : 0;
        int a1 = (i1 >= o) ? hist[i1 - o] : 0;
        __syncthreads();
        hist[i0] += a0; hist[i1] += a1;
        __syncthreads();
    }
    int e0 = hist[i0] - v0, e1 = hist[i1] - v1;
    __syncthreads();
    hist[i0] = e0; hist[i1] = e1;
    int* offg = iskg ? off_kg : off_ui;
    if (i0 < nkeys) offg[key_base + i0] = ebeg + e0;
    if (i1 < nkeys) offg[key_base + i1] = ebeg + e1;
    if (blockIdx.x == 0 && tid == 0) {
        off_kg[N_ENT]   = boff_kg[NB_KG];
        off_ui[N_NODES] = boff_ui[NB_UI];
    }
    __syncthreads();
    for (int i = tid; i < ne; i += 256) {
        unsigned int r = rec[i];
        int k = r >> SH;
        int slot = atomicAdd(&hist[k], 1);
        if (iskg) kgrec[ebeg + slot] = r & 0x7FFFFFu;
        else      { uirec[ebeg + slot] = (int)(r & 0x3FFFFu); uval[ebeg + slot] = fval[i]; }
    }
}

// ---------------------------------------------------------------------------
// kgagg_build: TWO NODES PER WAVE, one per half-wave (32 lanes).
// Avg KG degree ~10 means per-wave fixed costs (4-deep prologue load chain,
// expf/rsqrt epilogue) dominate — pairing amortizes them 2x and doubles
// per-wave memory-level parallelism. N_USERS even -> pairs never straddle
// the user/item boundary (whole wave takes one branch). All shuffles stay
// within a half (xor 16 / 1 / 2 / 4 / 8).
// Half layout: 16 lanes x uint2 per row (dims 4ql..4ql+3), 2 edge slots.
// Tail verified for deg%4 in {1,2,3}: each edge covered exactly once.
// ---------------------------------------------------------------------------
__global__ __launch_bounds__(256) void kgagg_build(const int* __restrict__ off,
                                                   const unsigned int* __restrict__ packed,
                                                   const unsigned short* __restrict__ y16,
                                                   const float* __restrict__ entity_emb,
                                                   const float* __restrict__ user_emb,
                                                   const int* __restrict__ i2e,
                                                   const float4* __restrict__ gate4,
                                                   float* __restrict__ all_emb,
                                                   unsigned short* __restrict__ all16) {
    int lane = threadIdx.x & 63;
    int half = lane >> 5;          // which node of the pair
    int hl   = lane & 31;
    int duo  = hl >> 4;            // edge slot within half
    int ql   = hl & 15;            // dims 4ql..4ql+3
    long wpair = (long)((blockIdx.x * 256 + threadIdx.x) >> 6);
    int w = (int)(wpair * 2 + half);
    if (w >= N_NODES) return;      // N_NODES even: whole wave exits together

    if (w < N_USERS) {             // both halves users: bf16 copy only
        if (duo == 0) {
            float4 v = ((const float4*)user_emb)[(long)w * 16 + ql];
            ((uint2*)all16)[(long)w * 16 + ql] =
                make_uint2((unsigned)f2bf(v.x) | ((unsigned)f2bf(v.y) << 16),
                           (unsigned)f2bf(v.z) | ((unsigned)f2bf(v.w) << 16));
        }
        return;
    }

    int ent = i2e[w - N_USERS];    // half-uniform (broadcast load)
    const uint2* y2 = (const uint2*)y16;
    int beg = off[ent], end = off[ent + 1];
    float a0 = 0.f, a1 = 0.f, a2 = 0.f, a3 = 0.f;
    float b0 = 0.f, b1 = 0.f, b2 = 0.f, b3 = 0.f;
    int p = beg;
    for (; p + 4 <= end; p += 4) {     // 4 edges per half per iter
        unsigned pk0 = packed[p + duo];
        unsigned pk1 = packed[p + 2 + duo];
        uint2 v0 = y2[(long)(pk0 & 0x3FFFF) * 16 + ql];
        uint2 v1 = y2[(long)(pk1 & 0x3FFFF) * 16 + ql];
        float4 g0 = gate4[(pk0 >> 18) * 16 + ql];
        float4 g1 = gate4[(pk1 >> 18) * 16 + ql];
        a0 += bf_lo(v0.x) * g0.x;  a1 += bf_hi(v0.x) * g0.y;
        a2 += bf_lo(v0.y) * g0.z;  a3 += bf_hi(v0.y) * g0.w;
        b0 += bf_lo(v1.x) * g1.x;  b1 += bf_hi(v1.x) * g1.y;
        b2 += bf_lo(v1.y) * g1.z;  b3 += bf_hi(v1.y) * g1.w;
    }
    if (p + duo < end) {               // tail edges p..p+1
        unsigned pk = packed[p + duo];
        uint2 v = y2[(long)(pk & 0x3FFFF) * 16 + ql];
        float4 g = gate4[(pk >> 18) * 16 + ql];
        a0 += bf_lo(v.x) * g.x;  a1 += bf_hi(v.x) * g.y;
        a2 += bf_lo(v.y) * g.z;  a3 += bf_hi(v.y) * g.w;
    }
    if (p + 2 + duo < end) {           // tail edge p+2 (p+3 impossible)
        unsigned pk = packed[p + 2 + duo];
        uint2 v = y2[(long)(pk & 0x3FFFF) * 16 + ql];
        float4 g = gate4[(pk >> 18) * 16 + ql];
        b0 += bf_lo(v.x) * g.x;  b1 += bf_hi(v.x) * g.y;
        b2 += bf_lo(v.y) * g.z;  b3 += bf_hi(v.y) * g.w;
    }
    a0 += b0; a1 += b1; a2 += b2; a3 += b3;
    a0 += __shfl_xor(a0, 16);          // merge the two duo slots (within half)
    a1 += __shfl_xor(a1, 16);
    a2 += __shfl_xor(a2, 16);
    a3 += __shfl_xor(a3, 16);

    float deg = fmaxf((float)(end - beg), 1.0f);
    float4 xv = ((const float4*)entity_emb)[(long)ent * 16 + ql];
    float v0 = a0 / deg + xv.x;
    float v1 = a1 / deg + xv.y;
    float v2 = a2 / deg + xv.z;
    float v3 = a3 / deg + xv.w;
    v0 = (v0 > 0.0f) ? v0 : (__expf(v0) - 1.0f);
    v1 = (v1 > 0.0f) ? v1 : (__expf(v1) - 1.0f);
    v2 = (v2 > 0.0f) ? v2 : (__expf(v2) - 1.0f);
    v3 = (v3 > 0.0f) ? v3 : (__expf(v3) - 1.0f);
    float ss = v0 * v0 + v1 * v1 + v2 * v2 + v3 * v3;
    ss += __shfl_xor(ss, 1);
    ss += __shfl_xor(ss, 2);
    ss += __shfl_xor(ss, 4);
    ss += __shfl_xor(ss, 8);
    float inv = 1.0f / fmaxf(sqrtf(ss), 1e-12f);
    if (duo == 0) {
        float r0 = v0 * inv, r1 = v1 * inv, r2 = v2 * inv, r3 = v3 * inv;
        ((float4*)all_emb)[(long)w * 16 + ql] = make_float4(r0, r1, r2, r3);
        ((uint2*)all16)[(long)w * 16 + ql] =
            make_uint2((unsigned)f2bf(r0) | ((unsigned)f2bf(r1) << 16),
                       (unsigned)f2bf(r2) | ((unsigned)f2bf(r3) << 16));
    }
}

// ---------------------------------------------------------------------------
// ui_aggregate_s: TWO SAMPLE ROWS PER WAVE (same half-wave transform).
// B even -> pairs never straddle the u/ipos/ineg segment boundaries.
// Duplicate rows across halves/waves write identical values (benign).
// ---------------------------------------------------------------------------
__global__ __launch_bounds__(256) void ui_aggregate_s(const int* __restrict__ off,
                                                      const int* __restrict__ colrec,
                                                      const float* __restrict__ uval,
                                                      const float* __restrict__ all_emb,
                                                      const float* __restrict__ user_emb,
                                                      const unsigned short* __restrict__ all16,
                                                      const int* __restrict__ u,
                                                      const int* __restrict__ ipos,
                                                      const int* __restrict__ ineg,
                                                      float* __restrict__ final_emb, int B) {
    const uint2* a2p = (const uint2*)all16;
    int lane = threadIdx.x & 63;
    int half = lane >> 5;
    int hl   = lane & 31;
    int duo  = hl >> 4;
    int ql   = hl & 15;
    long wpair = (long)((blockIdx.x * 256 + threadIdx.x) >> 6);
    int s = (int)(wpair * 2 + half);
    if (s >= 3 * B) return;            // 3B even: whole wave exits together
    int r;
    if (s < B)          r = u[s];
    else if (s < 2 * B) r = N_USERS + ipos[s - B];
    else                r = N_USERS + ineg[s - 2 * B];

    int beg = off[r], end = off[r + 1];
    float a0 = 0.f, a1 = 0.f, a2 = 0.f, a3 = 0.f;
    float b0 = 0.f, b1 = 0.f, b2 = 0.f, b3 = 0.f;
    int p = beg;
    for (; p + 4 <= end; p += 4) {
        int   c0 = colrec[p + duo];
        int   c1 = colrec[p + 2 + duo];
        float d0 = uval[p + duo];
        float d1 = uval[p + 2 + duo];
        uint2 v0 = a2p[(long)c0 * 16 + ql];
        uint2 v1 = a2p[(long)c1 * 16 + ql];
        a0 += d0 * bf_lo(v0.x);  a1 += d0 * bf_hi(v0.x);
        a2 += d0 * bf_lo(v0.y);  a3 += d0 * bf_hi(v0.y);
        b0 += d1 * bf_lo(v1.x);  b1 += d1 * bf_hi(v1.x);
        b2 += d1 * bf_lo(v1.y);  b3 += d1 * bf_hi(v1.y);
    }
    if (p + duo < end) {
        int   c = colrec[p + duo];
        float d = uval[p + duo];
        uint2 v = a2p[(long)c * 16 + ql];
        a0 += d * bf_lo(v.x);  a1 += d * bf_hi(v.x);
        a2 += d * bf_lo(v.y);  a3 += d * bf_hi(v.y);
    }
    if (p + 2 + duo < end) {
        int   c = colrec[p + 2 + duo];
        float d = uval[p + 2 + duo];
        uint2 v = a2p[(long)c * 16 + ql];
        b0 += d * bf_lo(v.x);  b1 += d * bf_hi(v.x);
        b2 += d * bf_lo(v.y);  b3 += d * bf_hi(v.y);
    }
    a0 += b0; a1 += b1; a2 += b2; a3 += b3;
    a0 += __shfl_xor(a0, 16);
    a1 += __shfl_xor(a1, 16);
    a2 += __shfl_xor(a2, 16);
    a3 += __shfl_xor(a3, 16);
    if (duo == 0) {
        float4 ae = (r < N_USERS)
            ? ((const float4*)user_emb)[(long)r * 16 + ql]
            : ((const float4*)all_emb)[(long)r * 16 + ql];
        ((float4*)final_emb)[(long)r * 16 + ql] =
            make_float4(0.5f * (ae.x + a0), 0.5f * (ae.y + a1),
                        0.5f * (ae.z + a2), 0.5f * (ae.w + a3));
    }
}

// ---------------------------------------------------------------------------
// Epilogue (intent folded in): one wave per sample.
// ---------------------------------------------------------------------------
__global__ void final_kernel(const int* __restrict__ u, const int* __restrict__ ipos,
                             const int* __restrict__ ineg,
                             const float* __restrict__ final_emb,
                             const float* __restrict__ all_emb,
                             const float* __restrict__ rw, const float* __restrict__ rb,
                             const float* __restrict__ iw, const float* __restrict__ rel_emb,
                             float* __restrict__ out, int B) {
    __shared__ float sh_intent[128];
    if (threadIdx.x < 64) {
        int j = threadIdx.x;
        for (int k = 0; k < 2; k++) {
            float m = -1e30f;
            for (int r = 0; r < N_REL; r++) m = fmaxf(m, iw[k * N_REL + r]);
            float Z = 0.f, acc = 0.f;
            for (int r = 0; r < N_REL; r++) {
                float e = __expf(iw[k * N_REL + r] - m);
                Z += e;
                acc += e * rel_emb[r * 64 + j];
            }
            sh_intent[k * 64 + j] = acc / Z;
        }
    }
    __syncthreads();
    int lane = threadIdx.x & 63;
    int wave = (blockIdx.x * blockDim.x + threadIdx.x) >> 6;
    int nw   = (gridDim.x * blockDim.x) >> 6;
    for (int b = wave; b < B; b += nw) {
        int uu = u[b];
        float up = final_emb[(long)uu * 64 + lane];
        float l0 = up * rw[lane];
        float l1 = up * rw[64 + lane];
        #pragma unroll
        for (int o = 32; o; o >>= 1) {
            l0 += __shfl_xor(l0, o);
            l1 += __shfl_xor(l1, o);
        }
        l0 += rb[0]; l1 += rb[1];
        float m  = fmaxf(l0, l1);
        float e0 = __expf(l0 - m), e1 = __expf(l1 - m);
        float inv = 1.0f / (e0 + e1);
        float p0 = e0 * inv, p1 = e1 * inv;
        float ue = up + p0 * sh_intent[lane] + p1 * sh_intent[64 + lane];

        int it = ipos[b];
        long rr = (long)(N_USERS + it) * 64 + lane;
        float ie = final_emb[rr] + all_emb[rr];
        float dp = ue * ie;
        #pragma unroll
        for (int o = 32; o; o >>= 1) dp += __shfl_xor(dp, o);
        if (lane == 0) out[b] = dp;

        it = ineg[b];
        rr = (long)(N_USERS + it) * 64 + lane;
        ie = final_emb[rr] + all_emb[rr];
        dp = ue * ie;
        #pragma unroll
        for (int o = 32; o; o >>= 1) dp += __shfl_xor(dp, o);
        if (lane == 0) out[B + b] = dp;
    }
}

extern "C" void kernel_launch(void* const* d_in, const int* in_sizes, int n_in,
                              void* d_out, int out_size, void* d_ws, size_t ws_size,
                              hipStream_t stream) {
    const int*   u          = (const int*)  d_in[0];
    const int*   ipos       = (const int*)  d_in[1];
    const int*   ineg       = (const int*)  d_in[2];
    const float* user_emb   = (const float*)d_in[3];
    const float* entity_emb = (const float*)d_in[4];
    const float* rel_emb    = (const float*)d_in[5];
    const float* iw         = (const float*)d_in[6];
    const float* rw         = (const float*)d_in[7];
    const float* rb         = (const float*)d_in[8];
    const float* kgw        = (const float*)d_in[9];
    const float* ui_vals    = (const float*)d_in[10];
    const int*   i2e        = (const int*)  d_in[11];
    const int*   kg_src     = (const int*)  d_in[12];
    const int*   kg_dst     = (const int*)  d_in[13];
    const int*   kg_rel     = (const int*)  d_in[14];
    const int*   ui_row     = (const int*)  d_in[15];
    const int*   ui_col     = (const int*)  d_in[16];
    float*       out        = (float*)d_out;

    int B    = in_sizes[0];
    int e_kg = in_sizes[12];
    int e_ui = in_sizes[15];

    // ---------------- workspace layout (bytes) ----------------
    char* ws = (char*)d_ws;
    unsigned short* y16       = (unsigned short*)(ws + 0);        // 25.6 MB
    float*          all_emb   = (float*)(ws + 25600000);          // 38.4 MB
    unsigned short* all16     = (unsigned short*)(ws + 64000000); // 19.2 MB
    float*          final_emb = (float*)(ws + 83200000);          // 38.4 MB (sparse use)
    unsigned int*   kgrec     = (unsigned int*)(ws + 121600000);  // 8 MB
    int*            uirec     = (int*)(ws + 129600000);           // 4 MB
    float*          uval      = (float*)(ws + 133600000);         // 4 MB
    int*            off_kg    = (int*)(ws + 137600000);           // 200001 ints
    int*            off_ui    = (int*)(ws + 138400256);           // 150001 ints
    unsigned*       ent_mask  = (unsigned*)(ws + 139000512);      // 25088 B (200K bits)
    unsigned*       node_mask = (unsigned*)(ws + 139025600);      // 18752 B (150K bits)
    int*            bcnt      = (int*)(ws + 139600512);           // 977 ints
    int*            boff_kg   = (int*)(ws + 139604480);           // 392 ints
    int*            boff_ui   = (int*)(ws + 139606272);           // 587 ints
    int*            bcur      = (int*)(ws + 139608704);           // 977 ints
    float2*         gateg     = (float2*)(ws + 139612672);        // 8 KB gate table

    hipMemsetAsync(ent_mask, 0, 25088 + 18752, stream);   // masks contiguous
    build_masks    <<<512, 256, 0, stream>>>(i2e, u, ipos, ineg, ent_mask, node_mask,
                                             bcnt, B);
    bucket_hist    <<<1024, 256, 0, stream>>>(kg_dst, ui_row, ent_mask, node_mask,
                                              rel_emb, gateg, bcnt, e_kg, e_ui);
    bucket_scan    <<<1,   256, 0, stream>>>(bcnt, boff_kg, boff_ui, bcur);
    bucket_scatter <<<512, 256, 0, stream>>>(kg_src, kg_dst, kg_rel, ui_row, ui_col,
                                             ui_vals, ent_mask, node_mask,
                                             bcur, kgrec, uirec, uval, e_kg, e_ui);
    bucket_finalize<<<NB_TOT, 256, 0, stream>>>(boff_kg, boff_ui, kgrec, uirec, uval,
                                                off_kg, off_ui);

    ent_matmul <<<(N_ENT + 127) / 128, 128, 0, stream>>>(entity_emb, kgw, y16, N_ENT);
    {   // two nodes per wave
        int nwaves = (N_NODES + 1) / 2;
        int nblk   = (nwaves * 64 + 255) / 256;
        kgagg_build<<<nblk, 256, 0, stream>>>(
            off_kg, kgrec, y16, entity_emb, user_emb, i2e, (const float4*)gateg,
            all_emb, all16);
    }
    {   // two sample rows per wave
        int nwaves = (3 * B + 1) / 2;
        int nblk   = (nwaves * 64 + 255) / 256;
        ui_aggregate_s<<<nblk, 256, 0, stream>>>(
            off_ui, uirec, uval, all_emb, user_emb, all16, u, ipos, ineg, final_emb, B);
    }
    final_kernel<<<256, 256, 0, stream>>>(u, ipos, ineg, final_emb, all_emb,
                                          rw, rb, iw, rel_emb, out, B);
}